// Round 3
// baseline (4226.825 us; speedup 1.0000x reference)
//
#include <hip/hip_runtime.h>
#include <hip/hip_bf16.h>
#include <cstddef>
#include <cstdint>

typedef unsigned short u16;
typedef __attribute__((ext_vector_type(8))) short short8;
typedef __attribute__((ext_vector_type(4))) float f32x4;

constexpr int BB   = 16;
constexpr int E    = 768;
constexpr int DEPTH= 12;
constexpr int NH   = 12;
constexpr int FF   = 3072;
constexpr int NTOK = 1024;
constexpr int KEEP = 512;
constexpr float LN_EPS = 1e-5f;

__device__ __forceinline__ u16 f2b(float f) {
    __hip_bfloat16 h = __float2bfloat16(f);
    return *reinterpret_cast<u16*>(&h);
}

// ---------------- patchify: x (B,1,512,512) f32 -> patches (B,1024,256) bf16 ----------------
__global__ __launch_bounds__(256)
void patchify16(const float* __restrict__ x, u16* __restrict__ patches) {
    int i = blockIdx.x * 256 + threadIdx.x;        // 16*1024*256 total
    int k = i & 255;
    int n = (i >> 8) & 1023;
    int b = i >> 18;
    int gi = n >> 5, gj = n & 31;
    int pi = k >> 4, pj = k & 15;
    patches[i] = f2b(x[((size_t)b << 18) + (size_t)((gi << 4) + pi) * 512 + (gj << 4) + pj]);
}

// ---------------- f32 -> bf16 conversion of up to 4 concatenated arrays ----------------
__global__ __launch_bounds__(256)
void convert4(const float* __restrict__ s0, int n0, const float* __restrict__ s1, int n1,
              const float* __restrict__ s2, int n2, const float* __restrict__ s3, int n3,
              u16* __restrict__ dst, int total) {
    int i4 = (blockIdx.x * 256 + threadIdx.x) * 4;
    if (i4 >= total) return;
    const float* s; int off;
    if (i4 < n0) { s = s0; off = i4; }
    else if (i4 < n0 + n1) { s = s1; off = i4 - n0; }
    else if (i4 < n0 + n1 + n2) { s = s2; off = i4 - n0 - n1; }
    else { s = s3; off = i4 - n0 - n1 - n2; }
    float4 v = *(const float4*)(s + off);
    u16 u0 = f2b(v.x), u1 = f2b(v.y), u2 = f2b(v.z), u3 = f2b(v.w);
    u16 tmp[4] = {u0, u1, u2, u3};
    *(uint2*)(dst + i4) = *(uint2*)tmp;
}

// ---------------- block reduce helper ----------------
__device__ __forceinline__ float block_sum256(float v, float* sh) {
    #pragma unroll
    for (int m = 32; m; m >>= 1) v += __shfl_xor(v, m, 64);
    int w = threadIdx.x >> 6;
    __syncthreads();
    if ((threadIdx.x & 63) == 0) sh[w] = v;
    __syncthreads();
    return sh[0] + sh[1] + sh[2] + sh[3];
}

// ---------------- LayerNorm: in f32, out f32 or bf16, optional +pos ----------------
template<bool OUTBF, bool POS>
__global__ __launch_bounds__(256)
void ln_kernel(const float* __restrict__ in, void* __restrict__ outp,
               const float* __restrict__ w, const float* __restrict__ bias,
               const float* __restrict__ pos) {
    __shared__ float sh[4];
    int tok = blockIdx.x, t = threadIdx.x;
    const float* row = in + (size_t)tok * E;
    float v0 = row[t], v1 = row[t + 256], v2 = row[t + 512];
    float s = block_sum256(v0 + v1 + v2, sh);
    float mean = s * (1.0f / 768.0f);
    float d0 = v0 - mean, d1 = v1 - mean, d2 = v2 - mean;
    float s2 = block_sum256(d0*d0 + d1*d1 + d2*d2, sh);
    float rstd = rsqrtf(s2 * (1.0f / 768.0f) + LN_EPS);
    float r0 = d0 * rstd * w[t]       + bias[t];
    float r1 = d1 * rstd * w[t + 256] + bias[t + 256];
    float r2 = d2 * rstd * w[t + 512] + bias[t + 512];
    if (POS) {
        int n = tok & (NTOK - 1);
        const float* prow = pos + (size_t)n * E;
        r0 += prow[t]; r1 += prow[t + 256]; r2 += prow[t + 512];
    }
    if (OUTBF) {
        u16* orow = (u16*)outp + (size_t)tok * E;
        orow[t] = f2b(r0); orow[t + 256] = f2b(r1); orow[t + 512] = f2b(r2);
    } else {
        float* orow = (float*)outp + (size_t)tok * E;
        orow[t] = r0; orow[t + 256] = r1; orow[t + 512] = r2;
    }
}

// ---------------- per-batch stable argsort (bitonic on (val,idx)) ----------------
// ids_restore is written as FLOAT (harness reads whole d_out as f32)
__global__ __launch_bounds__(1024)
void sort_kernel(const float* __restrict__ noise, int* __restrict__ ids_keep,
                 float* __restrict__ mask_out, float* __restrict__ restore_out) {
    __shared__ float sv[1024];
    __shared__ int   si[1024];
    int b = blockIdx.x, t = threadIdx.x;
    sv[t] = noise[b * 1024 + t];
    si[t] = t;
    __syncthreads();
    for (int k = 2; k <= 1024; k <<= 1) {
        for (int j = k >> 1; j > 0; j >>= 1) {
            int p = t ^ j;
            if (p > t) {
                bool up = ((t & k) == 0);
                float a = sv[t], c = sv[p];
                int ia = si[t], ic = si[p];
                bool sw = up ? (a > c || (a == c && ia > ic))
                             : (a < c || (a == c && ia < ic));
                if (sw) { sv[t] = c; sv[p] = a; si[t] = ic; si[p] = ia; }
            }
            __syncthreads();
        }
    }
    int idx = si[t];
    if (t < KEEP) ids_keep[b * KEEP + t] = idx;
    restore_out[b * 1024 + idx] = (float)t;
    mask_out[b * 1024 + idx] = (t < KEEP) ? 0.0f : 1.0f;
}

// ---------------- gather kept tokens (f32 -> f32) ----------------
__global__ __launch_bounds__(256)
void gather_kernel(const float* __restrict__ t, const int* __restrict__ keep,
                   float* __restrict__ X) {
    int tok = blockIdx.x;              // b*512 + i
    int b = tok >> 9;
    int src = keep[tok];
    const float* s = t + ((size_t)(b << 10) + src) * E;
    float* d = X + (size_t)tok * E;
    int tid = threadIdx.x;
    d[tid]       = s[tid];
    d[tid + 256] = s[tid + 256];
    d[tid + 512] = s[tid + 512];
}

// ---------------- bf16 MFMA GEMM: C = act(A @ W^T + bias) [+R], 128x128 tile ----------------
// A: M x K bf16 row-major.  W: N x K bf16 row-major.  C: M x N (f32 or bf16).
template<bool GELU, bool RES, bool OUTBF>
__global__ __launch_bounds__(256)
void mfma_gemm(const u16* __restrict__ A, const u16* __restrict__ W,
               const float* __restrict__ bias, const float* __restrict__ R,
               void* __restrict__ Cout, int M, int N, int K) {
    __shared__ u16 As[128 * 32];
    __shared__ u16 Ws[128 * 32];
    int tid = threadIdx.x;
    int lane = tid & 63, w = tid >> 6;
    int m0 = blockIdx.y << 7, n0 = blockIdx.x << 7;
    int wr = (w >> 1) << 6;            // wave row offset: 0 / 64
    int wc = (w & 1) << 6;             // wave col offset: 0 / 64
    int r16 = lane & 15, kq = lane >> 4;

    f32x4 acc[4][4];
    #pragma unroll
    for (int i = 0; i < 4; ++i)
        #pragma unroll
        for (int j = 0; j < 4; ++j) acc[i][j] = (f32x4)0.0f;

    // staging addresses: wave w covers segments {2w, 2w+1}; each seg = 16 rows x 32 cols bf16 = 1024B
    int seg = w * 2;
    const u16* gA = A + (size_t)(m0 + seg * 16 + (lane >> 2)) * K + (lane & 3) * 8;
    const u16* gW = W + (size_t)(n0 + seg * 16 + (lane >> 2)) * K + (lane & 3) * 8;
    u16* lA = As + seg * 512;
    u16* lW = Ws + seg * 512;
    const size_t rowK16 = (size_t)16 * K;

    for (int k0 = 0; k0 < K; k0 += 32) {
        __syncthreads();   // previous tile's reads complete before overwrite
        __builtin_amdgcn_global_load_lds((const __attribute__((address_space(1))) void*)(gA + k0),
                                         (__attribute__((address_space(3))) void*)(lA), 16, 0, 0);
        __builtin_amdgcn_global_load_lds((const __attribute__((address_space(1))) void*)(gA + k0 + rowK16),
                                         (__attribute__((address_space(3))) void*)(lA + 512), 16, 0, 0);
        __builtin_amdgcn_global_load_lds((const __attribute__((address_space(1))) void*)(gW + k0),
                                         (__attribute__((address_space(3))) void*)(lW), 16, 0, 0);
        __builtin_amdgcn_global_load_lds((const __attribute__((address_space(1))) void*)(gW + k0 + rowK16),
                                         (__attribute__((address_space(3))) void*)(lW + 512), 16, 0, 0);
        __syncthreads();   // vmcnt(0) drained by barrier semantics
        short8 af[4], bf[4];
        #pragma unroll
        for (int t = 0; t < 4; ++t) af[t] = *(const short8*)(As + (wr + t * 16 + r16) * 32 + kq * 8);
        #pragma unroll
        for (int t = 0; t < 4; ++t) bf[t] = *(const short8*)(Ws + (wc + t * 16 + r16) * 32 + kq * 8);
        #pragma unroll
        for (int i = 0; i < 4; ++i)
            #pragma unroll
            for (int j = 0; j < 4; ++j)
                acc[i][j] = __builtin_amdgcn_mfma_f32_16x16x32_bf16(af[i], bf[j], acc[i][j], 0, 0, 0);
    }

    // epilogue: D layout col=lane&15, row=(lane>>4)*4+reg
    #pragma unroll
    for (int i = 0; i < 4; ++i) {
        int row = m0 + wr + i * 16 + kq * 4;
        #pragma unroll
        for (int j = 0; j < 4; ++j) {
            int col = n0 + wc + j * 16 + r16;
            float bcol = bias[col];
            #pragma unroll
            for (int rg = 0; rg < 4; ++rg) {
                size_t off = (size_t)(row + rg) * N + col;
                float v = acc[i][j][rg] + bcol;
                if (GELU) v = 0.5f * v * (1.0f + erff(v * 0.70710678118654752f));
                if (RES)  v += R[off];
                if (OUTBF) ((u16*)Cout)[off] = f2b(v);
                else       ((float*)Cout)[off] = v;
            }
        }
    }
}

// ---------------- MFMA flash attention ----------------
// qkv: (B,512,2304) bf16, layout [c*768 + h*64 + d]; out: (B,512,768) bf16
__global__ __launch_bounds__(256)
void attn_mfma(const u16* __restrict__ qkv, u16* __restrict__ out) {
    __shared__ u16 Ks[64 * 80];   // [kpos][d], pad to 80
    __shared__ u16 Vt[64 * 80];   // [d][kpos]
    __shared__ u16 Ps[64 * 80];   // [qrow][kpos]
    int tid = threadIdx.x, lane = tid & 63, w = tid >> 6;
    int bh = blockIdx.y;
    int b = bh / NH, h = bh - b * NH;
    int q0 = blockIdx.x << 6;
    int r16 = lane & 15, kq = lane >> 4;
    const u16* base = qkv + (size_t)b * 512 * 2304 + h * 64;

    // Q fragments (A-operand): row = lane&15 within wave's 16 rows, k(d) = kq*8 + j (+32)
    const u16* qrow = base + (size_t)(q0 + w * 16 + r16) * 2304 + kq * 8;
    short8 qa0 = *(const short8*)(qrow);
    short8 qa1 = *(const short8*)(qrow + 32);

    f32x4 o[4];
    #pragma unroll
    for (int dt = 0; dt < 4; ++dt) o[dt] = (f32x4)0.0f;
    float mrow[4], lrow[4];
    #pragma unroll
    for (int r = 0; r < 4; ++r) { mrow[r] = -1e30f; lrow[r] = 0.0f; }

    for (int kt = 0; kt < 8; ++kt) {
        int k0 = kt << 6;
        __syncthreads();
        // stage K (natural) and V (transposed) tiles
        #pragma unroll
        for (int i = 0; i < 2; ++i) {
            int v = tid + 256 * i;
            int kp = v >> 3, d8 = (v & 7) * 8;
            short8 kv = *(const short8*)(base + (size_t)(k0 + kp) * 2304 + 768 + d8);
            *(short8*)(Ks + kp * 80 + d8) = kv;
            short8 vv = *(const short8*)(base + (size_t)(k0 + kp) * 2304 + 1536 + d8);
            #pragma unroll
            for (int j = 0; j < 8; ++j) Vt[(d8 + j) * 80 + kp] = (u16)vv[j];
        }
        __syncthreads();
        // S = Q K^T  (4 col-tiles of 16)
        f32x4 s[4];
        #pragma unroll
        for (int ct = 0; ct < 4; ++ct) {
            short8 kb0 = *(const short8*)(Ks + (ct * 16 + r16) * 80 + kq * 8);
            short8 kb1 = *(const short8*)(Ks + (ct * 16 + r16) * 80 + kq * 8 + 32);
            s[ct] = (f32x4)0.0f;
            s[ct] = __builtin_amdgcn_mfma_f32_16x16x32_bf16(qa0, kb0, s[ct], 0, 0, 0);
            s[ct] = __builtin_amdgcn_mfma_f32_16x16x32_bf16(qa1, kb1, s[ct], 0, 0, 0);
            s[ct] *= 0.125f;
        }
        // online softmax; lane's rows r = kq*4+reg, cols ct*16+r16
        float alpha[4];
        #pragma unroll
        for (int r = 0; r < 4; ++r) {
            float mx = fmaxf(fmaxf(s[0][r], s[1][r]), fmaxf(s[2][r], s[3][r]));
            #pragma unroll
            for (int msk = 1; msk < 16; msk <<= 1) mx = fmaxf(mx, __shfl_xor(mx, msk, 64));
            float mnew = fmaxf(mrow[r], mx);
            alpha[r] = expf(mrow[r] - mnew);
            mrow[r] = mnew;
            float ls = 0.0f;
            #pragma unroll
            for (int ct = 0; ct < 4; ++ct) {
                float p = expf(s[ct][r] - mnew);
                s[ct][r] = p; ls += p;
            }
            #pragma unroll
            for (int msk = 1; msk < 16; msk <<= 1) ls += __shfl_xor(ls, msk, 64);
            lrow[r] = lrow[r] * alpha[r] + ls;
        }
        // write P tile (bf16) into wave-private rows of Ps
        #pragma unroll
        for (int ct = 0; ct < 4; ++ct)
            #pragma unroll
            for (int r = 0; r < 4; ++r)
                Ps[(w * 16 + kq * 4 + r) * 80 + ct * 16 + r16] = f2b(s[ct][r]);
        // rescale O
        #pragma unroll
        for (int dt = 0; dt < 4; ++dt)
            #pragma unroll
            for (int r = 0; r < 4; ++r) o[dt][r] *= alpha[r];
        // PV: O += P @ V
        short8 pa0 = *(const short8*)(Ps + (w * 16 + r16) * 80 + kq * 8);
        short8 pa1 = *(const short8*)(Ps + (w * 16 + r16) * 80 + kq * 8 + 32);
        #pragma unroll
        for (int dt = 0; dt < 4; ++dt) {
            short8 vb0 = *(const short8*)(Vt + (dt * 16 + r16) * 80 + kq * 8);
            short8 vb1 = *(const short8*)(Vt + (dt * 16 + r16) * 80 + kq * 8 + 32);
            o[dt] = __builtin_amdgcn_mfma_f32_16x16x32_bf16(pa0, vb0, o[dt], 0, 0, 0);
            o[dt] = __builtin_amdgcn_mfma_f32_16x16x32_bf16(pa1, vb1, o[dt], 0, 0, 0);
        }
    }
    // epilogue
    #pragma unroll
    for (int dt = 0; dt < 4; ++dt)
        #pragma unroll
        for (int r = 0; r < 4; ++r) {
            float val = o[dt][r] / lrow[r];
            int row = q0 + w * 16 + kq * 4 + r;
            out[((size_t)b * 512 + row) * 768 + h * 64 + dt * 16 + r16] = f2b(val);
        }
}

// ---------------- host launch ----------------
extern "C" void kernel_launch(void* const* d_in, const int* in_sizes, int n_in,
                              void* d_out, int out_size, void* d_ws, size_t ws_size,
                              hipStream_t stream) {
    const float* x       = (const float*)d_in[0];
    const float* noise   = (const float*)d_in[1];
    const float* patch_w = (const float*)d_in[2];
    const float* patch_b = (const float*)d_in[3];
    const float* pe_w    = (const float*)d_in[4];
    const float* pe_b    = (const float*)d_in[5];
    const float* pos     = (const float*)d_in[6];
    const float* ln1_w   = (const float*)d_in[7];
    const float* ln1_b   = (const float*)d_in[8];
    const float* qkv_w   = (const float*)d_in[9];
    const float* qkv_b   = (const float*)d_in[10];
    const float* proj_w  = (const float*)d_in[11];
    const float* proj_b  = (const float*)d_in[12];
    const float* ln2_w   = (const float*)d_in[13];
    const float* ln2_b   = (const float*)d_in[14];
    const float* fc1_w   = (const float*)d_in[15];
    const float* fc1_b   = (const float*)d_in[16];
    const float* fc2_w   = (const float*)d_in[17];
    const float* fc2_b   = (const float*)d_in[18];
    const float* norm_w  = (const float*)d_in[19];
    const float* norm_b  = (const float*)d_in[20];

    float* out = (float*)d_out;
    char* ws = (char*)d_ws;

    // workspace layout (bytes)
    float* X     = (float*)(ws + 0);                  // 8192*768*4   = 25165824
    u16*   Hb16  = (u16*)  (ws + 25165824);           // 8192*768*2   = 12582912
    u16*   QKV16 = (u16*)  (ws + 37748736);           // 8192*2304*2  = 37748736
    u16*   FF16  = (u16*)  (ws + 75497472);           // 8192*3072*2  = 50331648
    u16*   AO16  = (u16*)  (ws + 125829120);          // 8192*768*2   = 12582912
    u16*   wbuf  = (u16*)  (ws + 138412032);          // 7077888*2    = 14155776
    u16*   pwbuf = (u16*)  (ws + 152567808);          // 196608*2     = 393216
    int*   keep  = (int*)  (ws + 152961024);          // 8192*4
    // pre-loop aliases (QKV16/FF16 regions are free before the layer loop)
    float* tfull   = (float*)QKV16;                   // 16384*768*4 = 50331648 (spans QKV16+FF16 head)
    u16*   pat16   = (u16*)(ws + 88080384);           // 16384*256*2 = 8388608 (inside FF16 tail region)

    float* mask_out    = out + (size_t)BB * KEEP * E;            // +6291456
    float* restore_out = mask_out + BB * NTOK;                   // +16384 (float!)

    // weight sub-offsets inside wbuf (elements)
    const int n_qkv = 3 * E * E;        // 1769472
    const int n_prj = E * E;            // 589824
    const int n_fc  = FF * E;           // 2359296
    u16* wq  = wbuf;
    u16* wp  = wbuf + n_qkv;
    u16* wf1 = wbuf + n_qkv + n_prj;
    u16* wf2 = wbuf + n_qkv + n_prj + n_fc;
    const int wtot = n_qkv + n_prj + 2 * n_fc;   // 7077888

    // 1. patch_w -> bf16
    convert4<<<192, 256, 0, stream>>>(patch_w, E * 256, patch_w, 0, patch_w, 0, patch_w, 0,
                                      pwbuf, E * 256);
    // 2. patchify -> bf16
    patchify16<<<16384, 256, 0, stream>>>(x, pat16);
    // 3. patch embed GEMM: (16384 x 256) @ (768 x 256)^T -> f32
    mfma_gemm<false, false, false><<<dim3(E / 128, (BB * NTOK) / 128), 256, 0, stream>>>(
        pat16, pwbuf, patch_b, nullptr, tfull, BB * NTOK, E, 256);
    // 4. LN + pos embed (f32 -> f32, in place)
    ln_kernel<false, true><<<BB * NTOK, 256, 0, stream>>>(tfull, tfull, pe_w, pe_b, pos);
    // 5. sort noise
    sort_kernel<<<BB, 1024, 0, stream>>>(noise, keep, mask_out, restore_out);
    // 6. gather kept tokens -> X f32
    gather_kernel<<<BB * KEEP, 256, 0, stream>>>(tfull, keep, X);

    const int M = BB * KEEP;   // 8192
    for (int l = 0; l < DEPTH; ++l) {
        convert4<<<wtot / 1024, 256, 0, stream>>>(
            qkv_w + (size_t)l * n_qkv, n_qkv, proj_w + (size_t)l * n_prj, n_prj,
            fc1_w + (size_t)l * n_fc, n_fc,  fc2_w + (size_t)l * n_fc, n_fc,
            wbuf, wtot);
        ln_kernel<true, false><<<M, 256, 0, stream>>>(X, Hb16, ln1_w + l * E, ln1_b + l * E, nullptr);
        mfma_gemm<false, false, true><<<dim3((3 * E) / 128, M / 128), 256, 0, stream>>>(
            Hb16, wq, qkv_b + (size_t)l * 3 * E, nullptr, QKV16, M, 3 * E, E);
        attn_mfma<<<dim3(KEEP / 64, BB * NH), 256, 0, stream>>>(QKV16, AO16);
        mfma_gemm<false, true, false><<<dim3(E / 128, M / 128), 256, 0, stream>>>(
            AO16, wp, proj_b + (size_t)l * E, X, X, M, E, E);
        ln_kernel<true, false><<<M, 256, 0, stream>>>(X, Hb16, ln2_w + l * E, ln2_b + l * E, nullptr);
        mfma_gemm<true, false, true><<<dim3(FF / 128, M / 128), 256, 0, stream>>>(
            Hb16, wf1, fc1_b + (size_t)l * FF, nullptr, FF16, M, FF, E);
        mfma_gemm<false, true, false><<<dim3(E / 128, M / 128), 256, 0, stream>>>(
            FF16, wf2, fc2_b + (size_t)l * E, X, X, M, E, FF);
    }
    // final LN -> x_vis (f32)
    ln_kernel<false, false><<<M, 256, 0, stream>>>(X, out, norm_w, norm_b, nullptr);
}